// Round 1
// baseline (366.848 us; speedup 1.0000x reference)
//
#include <hip/hip_runtime.h>

#define BSZ 8
#define LSEQ 8192
#define DDIM 256
#define CHUNK 128
#define WARM 64
#define NCH (LSEQ / CHUNK)  // 64

typedef float f32x4 __attribute__((ext_vector_type(4)));
typedef short bf16x8 __attribute__((ext_vector_type(8)));
typedef _Float16 h2 __attribute__((ext_vector_type(2)));

__device__ __forceinline__ unsigned short f2bf(float f) {
  unsigned u = __float_as_uint(f);
  return (unsigned short)((u + 0x7fffu + ((u >> 16) & 1u)) >> 16);  // RNE
}

#if __has_builtin(__builtin_amdgcn_fdot2)
#define FDOT2(a, b, c) __builtin_amdgcn_fdot2((a), (b), (c), false)
#else
__device__ __forceinline__ float fdot2_sw(h2 a, h2 b, float c) {
  return c + (float)a[0] * (float)b[0] + (float)a[1] * (float)b[1];
}
#define FDOT2(a, b, c) fdot2_sw((a), (b), (c))
#endif

// ---------------- conversions ----------------
__global__ void k_cvt_x(const float4* __restrict__ x4, ushort4* __restrict__ xb4) {
  int i = blockIdx.x * 256 + threadIdx.x;  // 4,194,304 threads, 4 elems each
  float4 v = x4[i];
  ushort4 o;
  o.x = f2bf(v.x); o.y = f2bf(v.y); o.z = f2bf(v.z); o.w = f2bf(v.w);
  xb4[i] = o;
}

__global__ void k_cvt_mats(const float* __restrict__ A, const float* __restrict__ B,
                           const float* __restrict__ C, _Float16* __restrict__ Ah,
                           unsigned short* __restrict__ Bb, unsigned short* __restrict__ Cb) {
  int i = blockIdx.x * 256 + threadIdx.x;  // 65536
  Ah[i] = (_Float16)A[i];
  Bb[i] = f2bf(B[i]);
  Cb[i] = f2bf(C[i]);
}

// ---------------- GEMM  (D = X @ W^T), X:(M,256) bf16 row-major, W:(256,256) bf16 row-major
// block = 256 threads (4 waves); block computes 32 rows x 256 cols; wave w -> cols [64w,64w+64)
__global__ __launch_bounds__(256, 4) void k_gemm_u(const short* __restrict__ Xb,
                                                   const short* __restrict__ Wb,
                                                   _Float16* __restrict__ U) {
  const int lane = threadIdx.x & 63, wave = threadIdx.x >> 6;
  const int l15 = lane & 15, quad = lane >> 4;
  const long r0 = (long)blockIdx.x * 32;
  const int c0 = wave * 64;
  f32x4 acc[2][4] = {};
#pragma unroll
  for (int kb = 0; kb < 256; kb += 32) {
    bf16x8 a0 = *(const bf16x8*)(Xb + (r0 + l15) * 256 + kb + quad * 8);
    bf16x8 a1 = *(const bf16x8*)(Xb + (r0 + 16 + l15) * 256 + kb + quad * 8);
#pragma unroll
    for (int ct = 0; ct < 4; ++ct) {
      bf16x8 b = *(const bf16x8*)(Wb + (c0 + ct * 16 + l15) * 256 + kb + quad * 8);
      acc[0][ct] = __builtin_amdgcn_mfma_f32_16x16x32_bf16(a0, b, acc[0][ct], 0, 0, 0);
      acc[1][ct] = __builtin_amdgcn_mfma_f32_16x16x32_bf16(a1, b, acc[1][ct], 0, 0, 0);
    }
  }
#pragma unroll
  for (int rt = 0; rt < 2; ++rt)
#pragma unroll
    for (int ct = 0; ct < 4; ++ct)
#pragma unroll
      for (int r = 0; r < 4; ++r) {
        long gi = r0 + rt * 16 + quad * 4 + r;
        int gj = c0 + ct * 16 + l15;
        U[gi * 256 + gj] = (_Float16)acc[rt][ct][r];
      }
}

__global__ __launch_bounds__(256, 4) void k_gemm_out(const short* __restrict__ Sb,
                                                     const short* __restrict__ Wb,
                                                     float* __restrict__ O) {
  const int lane = threadIdx.x & 63, wave = threadIdx.x >> 6;
  const int l15 = lane & 15, quad = lane >> 4;
  const long r0 = (long)blockIdx.x * 32;
  const int c0 = wave * 64;
  f32x4 acc[2][4] = {};
#pragma unroll
  for (int kb = 0; kb < 256; kb += 32) {
    bf16x8 a0 = *(const bf16x8*)(Sb + (r0 + l15) * 256 + kb + quad * 8);
    bf16x8 a1 = *(const bf16x8*)(Sb + (r0 + 16 + l15) * 256 + kb + quad * 8);
#pragma unroll
    for (int ct = 0; ct < 4; ++ct) {
      bf16x8 b = *(const bf16x8*)(Wb + (c0 + ct * 16 + l15) * 256 + kb + quad * 8);
      acc[0][ct] = __builtin_amdgcn_mfma_f32_16x16x32_bf16(a0, b, acc[0][ct], 0, 0, 0);
      acc[1][ct] = __builtin_amdgcn_mfma_f32_16x16x32_bf16(a1, b, acc[1][ct], 0, 0, 0);
    }
  }
#pragma unroll
  for (int rt = 0; rt < 2; ++rt)
#pragma unroll
    for (int ct = 0; ct < 4; ++ct)
#pragma unroll
      for (int r = 0; r < 4; ++r) {
        long gi = r0 + rt * 16 + quad * 4 + r;
        int gj = c0 + ct * 16 + l15;
        O[gi * 256 + gj] = acc[rt][ct][r];
      }
}

// ---------------- scan ----------------
// block = one (batch, chunk); thread j owns state column j; A[:,j] in VGPRs (fp16 pairs);
// state double-buffered in LDS (fp16); warm-up WARM steps from zero (||A^WARM|| <= 0.8^64 ~ 6e-7).
__global__ __launch_bounds__(256, 2) void k_scan(const _Float16* __restrict__ U,
                                                 const _Float16* __restrict__ Ah,
                                                 unsigned short* __restrict__ Sb) {
  __shared__ __align__(16) _Float16 st[2][DDIM];
  const int j = threadIdx.x;
  const int c = blockIdx.x & (NCH - 1);
  const int b = blockIdx.x >> 6;

  h2 a2[128];
#pragma unroll
  for (int m = 0; m < 128; ++m) {
    h2 t;
    t[0] = Ah[(2 * m) * 256 + j];
    t[1] = Ah[(2 * m + 1) * 256 + j];
    a2[m] = t;
  }
  st[0][j] = (_Float16)0.f;
  st[1][j] = (_Float16)0.f;
  __syncthreads();

  const int t0 = c * CHUNK;
  const int tstart = (t0 >= WARM) ? (t0 - WARM) : 0;
  const long baserow = (long)b * LSEQ;
  int cur = 0;
  for (int t = tstart; t < t0 + CHUNK; ++t) {
    float u = (float)U[(baserow + t) * 256 + j];  // issued early, consumed after dots
    const uint4* sq = (const uint4*)st[cur];
    float acc = 0.f;
#pragma unroll
    for (int blk = 0; blk < 32; ++blk) {
      union { uint4 q; h2 h[4]; } buf;
      buf.q = sq[blk];
#pragma unroll
      for (int r = 0; r < 4; ++r) acc = FDOT2(buf.h[r], a2[blk * 4 + r], acc);
    }
    float s = acc + u;
    st[cur ^ 1][j] = (_Float16)s;
    if (t >= t0) Sb[(baserow + t) * 256 + j] = f2bf(s);
    __syncthreads();
    cur ^= 1;
  }
}

extern "C" void kernel_launch(void* const* d_in, const int* in_sizes, int n_in,
                              void* d_out, int out_size, void* d_ws, size_t ws_size,
                              hipStream_t stream) {
  const float* x = (const float*)d_in[0];
  const float* A = (const float*)d_in[1];
  const float* B = (const float*)d_in[2];
  const float* C = (const float*)d_in[3];

  char* ws = (char*)d_ws;
  // ws layout: [0,32MB): xb (bf16), later overwritten by S (bf16). Then Ah/Bb/Cb.
  short* xb = (short*)ws;
  _Float16* Ah = (_Float16*)(ws + 33554432);
  unsigned short* Bb = (unsigned short*)(ws + 33554432 + 131072);
  unsigned short* Cb = (unsigned short*)(ws + 33554432 + 262144);
  _Float16* U = (_Float16*)d_out;  // 33.5MB in d_out's 67MB; dead before final store
  float* out = (float*)d_out;

  hipLaunchKernelGGL(k_cvt_x, dim3(16384), dim3(256), 0, stream, (const float4*)x, (ushort4*)xb);
  hipLaunchKernelGGL(k_cvt_mats, dim3(256), dim3(256), 0, stream, A, B, C, Ah, Bb, Cb);
  hipLaunchKernelGGL(k_gemm_u, dim3(2048), dim3(256), 0, stream, xb, (const short*)Bb, U);
  hipLaunchKernelGGL(k_scan, dim3(512), dim3(256), 0, stream, U, Ah, (unsigned short*)xb);
  hipLaunchKernelGGL(k_gemm_out, dim3(2048), dim3(256), 0, stream, (const short*)xb,
                     (const short*)Cb, out);
}